// Round 3
// baseline (1165.228 us; speedup 1.0000x reference)
//
#include <hip/hip_runtime.h>

#define BATCH 8
#define CCH 256
#define NPOS 4096
#define LOG2E 1.4426950408889634f

typedef __bf16 bf16x8 __attribute__((ext_vector_type(8)));
typedef float f32x4 __attribute__((ext_vector_type(4)));
typedef int i32x4 __attribute__((ext_vector_type(4)));
typedef unsigned short us4 __attribute__((ext_vector_type(4)));

#define CFENCE() __asm__ volatile("" ::: "memory")
// lgkmcnt(0), vmcnt no-wait, expcnt no-wait
#define WAIT_LGKM0() do { CFENCE(); __builtin_amdgcn_s_waitcnt(0xC07F); CFENCE(); } while (0)
#define BAR_RAW() do { CFENCE(); __builtin_amdgcn_s_barrier(); CFENCE(); } while (0)

__device__ __forceinline__ unsigned short f2bf(float f) {
  unsigned u = __builtin_bit_cast(unsigned, f);
  u += 0x7fffu + ((u >> 16) & 1u);
  return (unsigned short)(u >> 16);
}
__device__ __forceinline__ float bf2f(unsigned short s) {
  return __builtin_bit_cast(float, ((unsigned)s) << 16);
}
__device__ __forceinline__ bf16x8 ld_bf8(const unsigned short* p) {
  i32x4 t = *reinterpret_cast<const i32x4*>(p);
  return __builtin_bit_cast(bf16x8, t);
}

// ---------------------------------------------------------------- kernel 1
__global__ void cvt_kernel(const float* __restrict__ Wq,
                           const float* __restrict__ Wk,
                           const float* __restrict__ Wv,
                           unsigned short* __restrict__ dst)
{
  const int idx = blockIdx.x * 256 + threadIdx.x;   // 0..196607
  const float* src = (idx < 65536) ? Wq : ((idx < 131072) ? Wk : Wv);
  float v = src[idx & 65535];
  if (idx < 65536) v *= LOG2E;      // fold log2e into Q projection (exp2 softmax)
  dst[idx] = f2bf(v);
}

// ---------------------------------------------------------------- kernel 2
// One block per (b, 64-pos tile); z-loop over 4 o-phases reuses staged xT.
// q,k: direct packed 8B stores (no transpose needed for (N,C) layout).
// v: transpose via tbuf, coalesced b128 stores to (C,N).
__global__ __launch_bounds__(256, 3)
void qkv_kernel(const float* __restrict__ x,
                const unsigned short* __restrict__ Wall,   // Wq*log2e|Wk|Wv bf16
                const float* __restrict__ bq,
                const float* __restrict__ bk,
                const float* __restrict__ bv,
                unsigned short* __restrict__ qT,
                unsigned short* __restrict__ kT,
                unsigned short* __restrict__ vG)
{
  __shared__ __align__(16) unsigned short xT[64 * 264];   // 33792 B
  __shared__ __align__(16) unsigned short tbuf[64 * 72];  //  9216 B (v transpose)

  const int b   = blockIdx.x;
  const int i0  = blockIdx.y * 64;
  const int tid = threadIdx.x;
  const int w   = tid >> 6;
  const int l   = tid & 63;
  const int n   = l & 15;
  const int q4  = l >> 4;

  // stage x tile: thread = channel, float4 over positions
  {
    const float* xp = x + ((size_t)b * CCH + tid) * NPOS + i0;
#pragma unroll
    for (int it = 0; it < 16; ++it) {
      f32x4 f = *reinterpret_cast<const f32x4*>(xp + it * 4);
#pragma unroll
      for (int e = 0; e < 4; ++e) xT[(it * 4 + e) * 264 + tid] = f2bf(f[e]);
    }
  }
  __syncthreads();

  const size_t qbase = (size_t)b * NPOS * CCH;

  for (int z = 0; z < 4; ++z) {
    const int obase = z * 64;
    for (int s = 0; s < 3; ++s) {
      // A = W rows [obase + w*16 .. +16), register resident
      const unsigned short* Wp = Wall + s * 65536 + (size_t)(obase + w * 16 + n) * CCH + q4 * 8;
      bf16x8 wfr[8];
#pragma unroll
      for (int kk = 0; kk < 8; ++kk) wfr[kk] = ld_bf8(Wp + kk * 32);

      const float* bias = (s == 0) ? bq : (s == 1) ? bk : bv;
      const float bscale = (s == 0) ? LOG2E : 1.0f;
      float bo[4];
#pragma unroll
      for (int r = 0; r < 4; ++r) bo[r] = bias[obase + w * 16 + q4 * 4 + r] * bscale;

      f32x4 acc[4];
#pragma unroll
      for (int pt = 0; pt < 4; ++pt) {
        acc[pt] = {0.f, 0.f, 0.f, 0.f};
#pragma unroll
        for (int kk = 0; kk < 8; ++kk) {
          bf16x8 bfr = ld_bf8(&xT[(pt * 16 + n) * 264 + kk * 32 + q4 * 8]);
          acc[pt] = __builtin_amdgcn_mfma_f32_16x16x32_bf16(wfr[kk], bfr, acc[pt], 0, 0, 0);
        }
      }

      if (s < 2) {
        // direct packed store: row pos, 4 consecutive o in-lane (r-dim)
        unsigned short* dst = (s == 0 ? qT : kT) + qbase;
#pragma unroll
        for (int pt = 0; pt < 4; ++pt) {
          us4 pk = { f2bf(acc[pt][0] + bo[0]), f2bf(acc[pt][1] + bo[1]),
                     f2bf(acc[pt][2] + bo[2]), f2bf(acc[pt][3] + bo[3]) };
          *reinterpret_cast<us4*>(&dst[(size_t)(i0 + pt * 16 + n) * CCH + obase + w * 16 + q4 * 4]) = pk;
        }
      } else {
        __syncthreads();   // tbuf free (previous z's v-store consumed it)
#pragma unroll
        for (int pt = 0; pt < 4; ++pt)
#pragma unroll
          for (int r = 0; r < 4; ++r)
            tbuf[(w * 16 + q4 * 4 + r) * 72 + pt * 16 + n] = f2bf(acc[pt][r] + bo[r]);
        __syncthreads();
#pragma unroll
        for (int it = 0; it < 2; ++it) {
          const int idx = it * 256 + tid;
          const int o = idx >> 3, pw = (idx & 7) * 8;
          i32x4 d = *reinterpret_cast<const i32x4*>(&tbuf[o * 72 + pw]);
          *reinterpret_cast<i32x4*>(&vG[qbase + (size_t)(obase + o) * NPOS + i0 + pw]) = d;
        }
      }
    }
  }
}

// ---------------------------------------------------------------- kernel 3
// Flash attention. NZ=2: KV-range split, partial (O bf16, m, l) out; NZ=1: direct.
//  - K B-frags straight from global (L2/L1), rolling 4-frag register pipeline
//  - LDS only for P (XOR-swizzled, stride 64) + per-iter alpha stats
//  - l accumulated via ones-MFMA (no shfl sum-reduce); exp2 domain
template <int NZ>
__global__ __launch_bounds__(256, 3)
void attn_kernel(const unsigned short* __restrict__ qT,
                 const unsigned short* __restrict__ kT,
                 const unsigned short* __restrict__ vG,
                 const float* __restrict__ x,
                 const float* __restrict__ gamma,
                 float* __restrict__ out,
                 unsigned short* __restrict__ po,
                 float* __restrict__ ml)
{
  __shared__ __align__(16) unsigned short pbuf[64 * 64];  // 8192 B, swizzled
  __shared__ float stat_lds[64];

  const int b   = blockIdx.x;
  const int iy  = blockIdx.y;
  const int i0  = iy * 64;
  const int z   = (NZ == 2) ? blockIdx.z : 0;
  const int tid = threadIdx.x;
  const int w   = tid >> 6;
  const int l   = tid & 63;
  const int n   = l & 15;
  const int q4  = l >> 4;
  const int nsw = n & 7;

  const unsigned short* qTb = qT + (size_t)b * NPOS * CCH;
  const unsigned short* kTb = kT + (size_t)b * NPOS * CCH;
  const unsigned short* vb  = vG + (size_t)b * NPOS * CCH;

  // Q fragments register-resident (A[m=lane&15][k=quad*8+j])
  bf16x8 afr[8];
  {
    const unsigned short* qrow = qTb + (size_t)(i0 + w * 16 + n) * CCH + q4 * 8;
#pragma unroll
    for (int kk = 0; kk < 8; ++kk)
      afr[kk] = ld_bf8(qrow + kk * 32);
  }
  bf16x8 ones;
  {
    i32x4 t = { (int)0x3F803F80, (int)0x3F803F80, (int)0x3F803F80, (int)0x3F803F80 };
    ones = __builtin_bit_cast(bf16x8, t);
  }

  f32x4 O[16];   // [ct*4+it]: c in [w*64+ct*16,+16), i in [it*16,+16)
#pragma unroll
  for (int t = 0; t < 16; ++t) O[t] = {0.f, 0.f, 0.f, 0.f};
  f32x4 lacc = {0.f, 0.f, 0.f, 0.f};
  float mrow[4] = {-1e30f, -1e30f, -1e30f, -1e30f};

  const int JT = 64 / NZ;
  for (int jt = 0; jt < JT; ++jt) {
    const int j0 = z * (NPOS / NZ) + jt * 64;

    // ---- S = Q K^T : K B-frags direct from global, rolling 4-frag pipeline
    const unsigned short* rowptr = kTb + (size_t)j0 * CCH + n * CCH + q4 * 8;
    i32x4 ka[4], kb2[4];
#pragma unroll
    for (int kk = 0; kk < 4; ++kk) ka[kk] = *reinterpret_cast<const i32x4*>(rowptr + kk * 32);
    f32x4 sacc[4];
#pragma unroll
    for (int nt = 0; nt < 4; ++nt) {
      const unsigned short* rp = rowptr + nt * 16 * CCH;
#pragma unroll
      for (int kk = 0; kk < 4; ++kk) kb2[kk] = *reinterpret_cast<const i32x4*>(rp + (kk + 4) * 32);
      sacc[nt] = {0.f, 0.f, 0.f, 0.f};
#pragma unroll
      for (int kk = 0; kk < 4; ++kk)
        sacc[nt] = __builtin_amdgcn_mfma_f32_16x16x32_bf16(afr[kk], __builtin_bit_cast(bf16x8, ka[kk]), sacc[nt], 0, 0, 0);
      if (nt < 3) {
        const unsigned short* rn = rowptr + (nt + 1) * 16 * CCH;
#pragma unroll
        for (int kk = 0; kk < 4; ++kk) ka[kk] = *reinterpret_cast<const i32x4*>(rn + kk * 32);
      }
#pragma unroll
      for (int kk = 0; kk < 4; ++kk)
        sacc[nt] = __builtin_amdgcn_mfma_f32_16x16x32_bf16(afr[kk + 4], __builtin_bit_cast(bf16x8, kb2[kk]), sacc[nt], 0, 0, 0);
    }

    // ---- prefetch V[jt] into registers (consumed in PV, ~700 cyc later)
    i32x4 vreg[8];
#pragma unroll
    for (int ct = 0; ct < 4; ++ct) {
      const unsigned short* vp = vb + (size_t)(w * 64 + ct * 16 + n) * NPOS + j0 + q4 * 8;
      vreg[ct * 2]     = *reinterpret_cast<const i32x4*>(vp);
      vreg[ct * 2 + 1] = *reinterpret_cast<const i32x4*>(vp + 32);
    }

    // ---- online softmax (exp2 domain; max-reduce only, sum comes from MFMA)
    float a_r[4];
#pragma unroll
    for (int r = 0; r < 4; ++r) {
      float tm = fmaxf(fmaxf(sacc[0][r], sacc[1][r]), fmaxf(sacc[2][r], sacc[3][r]));
      tm = fmaxf(tm, __shfl_xor(tm, 1));
      tm = fmaxf(tm, __shfl_xor(tm, 2));
      tm = fmaxf(tm, __shfl_xor(tm, 4));
      tm = fmaxf(tm, __shfl_xor(tm, 8));
      const float mnew = fmaxf(mrow[r], tm);
      a_r[r] = __builtin_amdgcn_exp2f(mrow[r] - mnew);
#pragma unroll
      for (int nt = 0; nt < 4; ++nt)
        sacc[nt][r] = __builtin_amdgcn_exp2f(sacc[nt][r] - mnew);
      mrow[r] = mnew;
    }

    if (n == 0) {
#pragma unroll
      for (int r = 0; r < 4; ++r) stat_lds[w * 16 + q4 * 4 + r] = a_r[r];
    }
    // P -> LDS, XOR-swizzled: phys = row*64 + ((j>>3)^(row&7))*8 + (j&7)
#pragma unroll
    for (int r = 0; r < 4; ++r) {
      const int row = w * 16 + q4 * 4 + r;
      const int r7 = row & 7;
#pragma unroll
      for (int nt = 0; nt < 4; ++nt) {
        const int chunk = nt * 2 + (n >> 3);
        pbuf[row * 64 + (chunk ^ r7) * 8 + nsw] = f2bf(sacc[nt][r]);
      }
    }

    WAIT_LGKM0();   // my P/stat writes landed
    BAR_RAW();      // P + alpha visible; all waves past S

    // rescale O by alpha; accumulate l via ones-MFMA
    float al[4];
#pragma unroll
    for (int it = 0; it < 4; ++it) al[it] = stat_lds[it * 16 + n];

    bf16x8 pf[8];
#pragma unroll
    for (int it = 0; it < 4; ++it) {
      const int rw = it * 16 + n;
      const int r7 = rw & 7;
      pf[it * 2 + 0] = ld_bf8(&pbuf[rw * 64 + ((q4) ^ r7) * 8]);
      pf[it * 2 + 1] = ld_bf8(&pbuf[rw * 64 + ((4 + q4) ^ r7) * 8]);
    }

#pragma unroll
    for (int it = 0; it < 4; ++it) {
#pragma unroll
      for (int ct = 0; ct < 4; ++ct) {
        f32x4& o = O[ct * 4 + it];
        o[0] *= al[it]; o[1] *= al[it]; o[2] *= al[it]; o[3] *= al[it];
      }
    }
    lacc[0] *= al[w]; lacc[1] *= al[w]; lacc[2] *= al[w]; lacc[3] *= al[w];
    lacc = __builtin_amdgcn_mfma_f32_16x16x32_bf16(ones, pf[w * 2 + 0], lacc, 0, 0, 0);
    lacc = __builtin_amdgcn_mfma_f32_16x16x32_bf16(ones, pf[w * 2 + 1], lacc, 0, 0, 0);

    // PV: V from registers, P from LDS
#pragma unroll
    for (int ct = 0; ct < 4; ++ct) {
      bf16x8 vf0 = __builtin_bit_cast(bf16x8, vreg[ct * 2]);
      bf16x8 vf1 = __builtin_bit_cast(bf16x8, vreg[ct * 2 + 1]);
#pragma unroll
      for (int it = 0; it < 4; ++it) {
        O[ct * 4 + it] = __builtin_amdgcn_mfma_f32_16x16x32_bf16(vf0, pf[it * 2 + 0], O[ct * 4 + it], 0, 0, 0);
        O[ct * 4 + it] = __builtin_amdgcn_mfma_f32_16x16x32_bf16(vf1, pf[it * 2 + 1], O[ct * 4 + it], 0, 0, 0);
      }
    }

    BAR_RAW();      // pbuf/stat consumed by all; safe to rewrite next iter
  }

  if (NZ == 2) {
    // partial out: O bf16 [i][c], m + l fp32
    const int part = ((b * 64 + iy) * 2 + z);
    unsigned short* poB = po + (size_t)part * (64 * 256);
#pragma unroll
    for (int it = 0; it < 4; ++it) {
#pragma unroll
      for (int ct = 0; ct < 4; ++ct) {
        f32x4 o = O[ct * 4 + it];
        us4 pk = { f2bf(o[0]), f2bf(o[1]), f2bf(o[2]), f2bf(o[3]) };
        *reinterpret_cast<us4*>(&poB[(it * 16 + n) * 256 + w * 64 + ct * 16 + q4 * 4]) = pk;
      }
    }
    float* mlB = ml + (size_t)part * 128;
    if (n == 0) {
#pragma unroll
      for (int r = 0; r < 4; ++r) mlB[w * 16 + q4 * 4 + r] = mrow[r];
    }
    if (q4 == 0) mlB[64 + w * 16 + n] = lacc[0];
  } else {
    // direct epilogue: y = x + gamma * O / l
    __syncthreads();
    if (q4 == 0) stat_lds[w * 16 + n] = lacc[0];
    __syncthreads();
    const float g = gamma[0];
#pragma unroll
    for (int it = 0; it < 4; ++it) {
      const float sc = g / stat_lds[it * 16 + n];
      const int ipos = i0 + it * 16 + n;
#pragma unroll
      for (int ct = 0; ct < 4; ++ct) {
#pragma unroll
        for (int r = 0; r < 4; ++r) {
          const int c = w * 64 + ct * 16 + q4 * 4 + r;
          const size_t idx = ((size_t)(b * CCH + c)) * NPOS + ipos;
          out[idx] = x[idx] + sc * O[ct * 4 + it][r];
        }
      }
    }
  }
}

// ---------------------------------------------------------------- kernel 4
// Merge the two KV-range partials + residual. Memory-bound.
__global__ __launch_bounds__(256, 2)
void merge_kernel(const unsigned short* __restrict__ po,
                  const float* __restrict__ ml,
                  const float* __restrict__ x,
                  const float* __restrict__ gamma,
                  float* __restrict__ out)
{
  __shared__ float num[64 * 257];   // 65792 B, +1-dword pad via 257 stride
  __shared__ float a1s[64], a2s[64], dns[64];

  const int b  = blockIdx.x;
  const int iy = blockIdx.y;
  const int i0 = iy * 64;
  const int tid = threadIdx.x;
  const int p0 = (b * 64 + iy) * 2;

  if (tid < 64) {
    const float m1 = ml[(size_t)p0 * 128 + tid];
    const float l1 = ml[(size_t)p0 * 128 + 64 + tid];
    const float m2 = ml[(size_t)(p0 + 1) * 128 + tid];
    const float l2 = ml[(size_t)(p0 + 1) * 128 + 64 + tid];
    const float m = fmaxf(m1, m2);
    const float a1 = __builtin_amdgcn_exp2f(m1 - m);
    const float a2 = __builtin_amdgcn_exp2f(m2 - m);
    a1s[tid] = a1;
    a2s[tid] = a2;
    dns[tid] = gamma[0] / (l1 * a1 + l2 * a2);
  }
  __syncthreads();

  const unsigned short* po1 = po + (size_t)p0 * (64 * 256);
  const unsigned short* po2 = po1 + 64 * 256;
  for (int i = 0; i < 64; ++i) {
    num[i * 257 + tid] = bf2f(po1[i * 256 + tid]) * a1s[i] + bf2f(po2[i * 256 + tid]) * a2s[i];
  }
  __syncthreads();

  const int il = tid & 63;
  const int ch = tid >> 6;
  const float dn = dns[il];
#pragma unroll 4
  for (int k = 0; k < 64; ++k) {
    const int c = ch * 64 + k;
    const size_t idx = ((size_t)(b * CCH + c)) * NPOS + i0 + il;
    out[idx] = x[idx] + dn * num[il * 257 + c];
  }
}

// ---------------------------------------------------------------- launch
extern "C" void kernel_launch(void* const* d_in, const int* in_sizes, int n_in,
                              void* d_out, int out_size, void* d_ws, size_t ws_size,
                              hipStream_t stream)
{
  const float* x     = (const float*)d_in[0];
  const float* Wq    = (const float*)d_in[1];
  const float* bq    = (const float*)d_in[2];
  const float* Wk    = (const float*)d_in[3];
  const float* bk    = (const float*)d_in[4];
  const float* Wv    = (const float*)d_in[5];
  const float* bv    = (const float*)d_in[6];
  const float* gamma = (const float*)d_in[7];
  float* out = (float*)d_out;

  unsigned short* ws   = (unsigned short*)d_ws;
  unsigned short* Wall = ws;                                  // 3 x 65536 bf16
  unsigned short* qT   = ws + 196608;                         // (B,N,C) bf16
  unsigned short* kT   = qT + (size_t)BATCH * NPOS * CCH;     // (B,N,C) bf16
  unsigned short* vG   = kT + (size_t)BATCH * NPOS * CCH;     // (B,C,N) bf16
  unsigned short* po   = vG + (size_t)BATCH * NPOS * CCH;     // 1024 x 64 x 256 bf16
  float*          ml   = (float*)(po + (size_t)1024 * 64 * 256);  // 1024 x 128 fp32

  const size_t need_split = (size_t)((char*)(ml + 1024 * 128) - (char*)d_ws);

  cvt_kernel<<<768, 256, 0, stream>>>(Wq, Wk, Wv, Wall);
  qkv_kernel<<<dim3(8, 64), 256, 0, stream>>>(x, Wall, bq, bk, bv, qT, kT, vG);
  if (ws_size >= need_split) {
    attn_kernel<2><<<dim3(8, 64, 2), 256, 0, stream>>>(qT, kT, vG, x, gamma, out, po, ml);
    merge_kernel<<<dim3(8, 64), 256, 0, stream>>>(po, ml, x, gamma, out);
  } else {
    attn_kernel<1><<<dim3(8, 64), 256, 0, stream>>>(qT, kT, vG, x, gamma, out, po, ml);
  }
}